// Round 4
// baseline (1063.577 us; speedup 1.0000x reference)
//
#include <hip/hip_runtime.h>
#include <hip/hip_bf16.h>

// x: (R=64, C=256, B=4, E=768) fp32 ; query: (Q=256, B=4, QD=512)
// Wq: (768,512), Wk/Wv/Wo: (768,768), biases: (768,)  ; out: (R,C,B,E) fp32
// H=12, D=64, scaling = D^-0.5/sqrt(Q) = 1/128
//
// Decomposition:
//  xsum[rb,e]   = sum_c x[r,c,n,e]                       (rb = r*4+n)
//  ksum[rb,e]   = xsum @ Wk^T + 256*bk
//  qp[qb,e]     = (query @ Wq^T + bq) / 128              (qb = q*4+n)
//  psum[h,n,r]  = sum_q softmax_r( qp . ksum )
//  vtmp[m,e]    = bf16( (x @ Wv^T + bv) * psum[e>>6, m&3, m>>10] )
//  out[m,f]     = vtmp @ Wo^T + bo
// The two 65536x768x768 GEMMs run on MFMA (bf16 in, fp32 accum).

typedef __attribute__((ext_vector_type(8))) short bf16x8;
typedef __attribute__((ext_vector_type(4))) float f32x4;

__device__ __forceinline__ void load_lds16(const void* g, void* l) {
    __builtin_amdgcn_global_load_lds(
        (const __attribute__((address_space(1))) void*)g,
        (__attribute__((address_space(3))) void*)l, 16, 0, 0);
}

__device__ __forceinline__ unsigned short f2bf(float f) {
    union { __hip_bfloat16 h; unsigned short u; } cv;
    cv.h = __float2bfloat16(f);
    return cv.u;
}

// ---- pass 1: column-sum of x over c + fused fp32->bf16 conversion (float4) ----
// 49152 threads: gid -> (rb = gid/192, e4 = gid%192), loop c=0..255.
__global__ __launch_bounds__(256) void xsum_cvt_kernel(const float4* __restrict__ x4,
                                                       float4* __restrict__ xsum4,
                                                       ushort4* __restrict__ xb4) {
    int gid = blockIdx.x * 256 + threadIdx.x;   // 0 .. 49151
    int rb = gid / 192, e4 = gid % 192;
    int r = rb >> 2, n = rb & 3;
    size_t base = ((size_t)(r * 256) * 4 + n) * 192 + e4;  // float4 units
    float sx = 0.f, sy = 0.f, sz = 0.f, sw = 0.f;
    #pragma unroll 4
    for (int c = 0; c < 256; ++c) {
        float4 v = x4[base + (size_t)c * 768];
        sx += v.x; sy += v.y; sz += v.z; sw += v.w;
        ushort4 o;
        o.x = f2bf(v.x); o.y = f2bf(v.y); o.z = f2bf(v.z); o.w = f2bf(v.w);
        xb4[base + (size_t)c * 768] = o;
    }
    float4 s; s.x = sx; s.y = sy; s.z = sz; s.w = sw;
    xsum4[(size_t)rb * 192 + e4] = s;
}

// ---- weights fp32->bf16, both matrices in one dispatch ----
__global__ __launch_bounds__(256) void f2b_kernel(const float* __restrict__ Wv,
                                                  const float* __restrict__ Wo,
                                                  unsigned short* __restrict__ Wvb,
                                                  unsigned short* __restrict__ Wob) {
    int i = blockIdx.x * 256 + threadIdx.x;   // 0 .. 294911 float4s
    const float4* src; ushort4* dst; int j;
    if (i < 147456) { src = (const float4*)Wv; dst = (ushort4*)Wvb; j = i; }
    else            { src = (const float4*)Wo; dst = (ushort4*)Wob; j = i - 147456; }
    float4 v = src[j];
    ushort4 o;
    o.x = f2bf(v.x); o.y = f2bf(v.y); o.z = f2bf(v.z); o.w = f2bf(v.w);
    dst[j] = o;
}

// ---- small fp32 GEMMs (ksum + qp) fused into ONE dispatch ----
// by<4:  ksum = xsum @ Wk^T + 256*bk      (M=256,  K=768)
// by>=4: qp   = (query @ Wq^T + bq)/128   (M=1024, K=512)
__global__ __launch_bounds__(256) void small_gemms(const float* __restrict__ xsum,
                                                   const float* __restrict__ Wk,
                                                   const float* __restrict__ bk,
                                                   float* __restrict__ ksum,
                                                   const float* __restrict__ query,
                                                   const float* __restrict__ Wq,
                                                   const float* __restrict__ bq,
                                                   float* __restrict__ qp) {
    __shared__ float As[16][65];
    __shared__ float Ws[16][65];
    bool isk = blockIdx.y < 4;
    const float* A    = isk ? xsum : query;
    const float* W    = isk ? Wk : Wq;
    const float* bias = isk ? bk : bq;
    float* C          = isk ? ksum : qp;
    int K             = isk ? 768 : 512;
    int m0 = (isk ? blockIdx.y : blockIdx.y - 4) * 64;
    int n0 = blockIdx.x * 64;
    const int N = 768;

    int tid = threadIdx.x;
    int tx = tid & 15, ty = tid >> 4;
    float acc[4][4] = {};

    for (int k0 = 0; k0 < K; k0 += 16) {
        #pragma unroll
        for (int i = 0; i < 4; ++i) {
            int idx = tid + 256 * i;
            int mm = idx >> 4, kk = idx & 15;
            As[kk][mm] = A[(size_t)(m0 + mm) * K + k0 + kk];
            Ws[kk][mm] = W[(size_t)(n0 + mm) * K + k0 + kk];
        }
        __syncthreads();
        #pragma unroll
        for (int kk = 0; kk < 16; ++kk) {
            float a[4], b[4];
            #pragma unroll
            for (int i = 0; i < 4; ++i) a[i] = As[kk][ty + 16 * i];
            #pragma unroll
            for (int j = 0; j < 4; ++j) b[j] = Ws[kk][tx + 16 * j];
            #pragma unroll
            for (int i = 0; i < 4; ++i)
                #pragma unroll
                for (int j = 0; j < 4; ++j) acc[i][j] += a[i] * b[j];
        }
        __syncthreads();
    }
    #pragma unroll
    for (int i = 0; i < 4; ++i) {
        int m = m0 + ty + 16 * i;
        #pragma unroll
        for (int j = 0; j < 4; ++j) {
            int n = n0 + tx + 16 * j;
            float v = acc[i][j];
            if (isk) C[(size_t)m * N + n] = v + 256.0f * bias[n];
            else     C[(size_t)m * N + n] = (v + bias[n]) * 0.0078125f;
        }
    }
}

// ---- attention: scores + softmax over r + column-sum of probs ----
__global__ __launch_bounds__(256) void attn_kernel(const float* __restrict__ qp,
                                                   const float* __restrict__ ksum,
                                                   float* __restrict__ psum) {
    int h = blockIdx.x >> 2;
    int n = blockIdx.x & 3;
    __shared__ float kd[64][65];
    __shared__ float sacc[4][64];
    int tid = threadIdx.x;

    #pragma unroll
    for (int it = 0; it < 16; ++it) {
        int idx = tid + 256 * it;
        int r = idx >> 6, d = idx & 63;
        kd[r][d] = ksum[(size_t)(r * 4 + n) * 768 + h * 64 + d];
    }
    __syncthreads();

    int wave = tid >> 6, lane = tid & 63;
    float acc = 0.f;
    for (int q = wave; q < 256; q += 4) {
        float qv = qp[(size_t)(q * 4 + n) * 768 + h * 64 + lane];
        float val = 0.f;
        #pragma unroll
        for (int d = 0; d < 64; ++d) val += __shfl(qv, d) * kd[lane][d];
        float mx = val;
        #pragma unroll
        for (int off = 1; off < 64; off <<= 1) mx = fmaxf(mx, __shfl_xor(mx, off));
        float p = __expf(val - mx);
        float s = p;
        #pragma unroll
        for (int off = 1; off < 64; off <<= 1) s += __shfl_xor(s, off);
        acc += p / s;
    }
    sacc[wave][lane] = acc;
    __syncthreads();
    if (tid < 64) {
        psum[blockIdx.x * 64 + tid] =
            sacc[0][tid] + sacc[1][tid] + sacc[2][tid] + sacc[3][tid];
    }
}

// ---- MFMA bf16 GEMM: C = epilogue(A(MxK) @ W(NxK)^T) ----
// BM=BN=128, BK=32, 256 threads (4 waves, each a 64x64 quadrant of 4x4 MFMA).
// Epilogue does a per-wave LDS transpose so global stores are float4/ushort4
// full-cache-line writes (kills read-for-ownership overfetch).
// MODE 2: Cb = bf16((acc + bias[n]) * scale[((n>>6)*4 + (m&3))*64 + (m>>10)])
// MODE 3: Cf = acc + bias[n]
struct MfmaSmem {
    union {
        struct { short As[128 * 32]; short Bs[128 * 32]; } st;   // 16 KB staging
        float cscr[4][16 * 68];                                  // 17.4 KB epilogue
    };
};

template <int MODE>
__global__ __launch_bounds__(256, 3) void mfma_gemm(const ushort* __restrict__ A,
                                                    const ushort* __restrict__ W,
                                                    const float* __restrict__ bias,
                                                    const float* __restrict__ scale,
                                                    float* __restrict__ Cf,
                                                    __hip_bfloat16* __restrict__ Cb,
                                                    int M, int N, int K) {
    __shared__ MfmaSmem sm;
    int tid = threadIdx.x;
    int wave = tid >> 6, lane = tid & 63;
    int wr = wave >> 1, wc = wave & 1;           // 64x64 quadrant
    // XCD-aware swizzle: per-XCD m-bands, n-tile innermost (L2 A-reuse).
    int flat = blockIdx.x + 6 * blockIdx.y;      // 0..3071
    int xcd = flat & 7, slot = flat >> 3;        // 8 XCDs, 384 slots each
    int mt6 = slot / 6;
    int mtile = xcd * 64 + mt6;                  // 0..511
    int ntile = slot - mt6 * 6;                  // 0..5
    int m0 = mtile * 128, n0 = ntile * 128;
    int r16 = lane & 15, kg = lane >> 4;         // MFMA fragment coords

    f32x4 acc[4][4];
    #pragma unroll
    for (int i = 0; i < 4; ++i)
        #pragma unroll
        for (int j = 0; j < 4; ++j) acc[i][j] = (f32x4){0.f, 0.f, 0.f, 0.f};

    for (int k0 = 0; k0 < K; k0 += 32) {
        // stage A and B tiles: 512 chunks of 16B each (4 chunks per 32-short row)
        #pragma unroll
        for (int j = 0; j < 2; ++j) {
            int c = j * 256 + wave * 64 + lane;          // chunk 0..511
            int row = c >> 2, col8 = (c & 3) * 8;        // 4 chunks/row
            load_lds16(A + (size_t)(m0 + row) * K + k0 + col8,
                       &sm.st.As[(j * 256 + wave * 64) * 8]);  // dst = base + lane*16B
            load_lds16(W + (size_t)(n0 + row) * K + k0 + col8,
                       &sm.st.Bs[(j * 256 + wave * 64) * 8]);
        }
        __syncthreads();   // drains vmcnt (global_load_lds) before LDS reads

        bf16x8 af[4], bv[4];
        #pragma unroll
        for (int mi = 0; mi < 4; ++mi)
            af[mi] = *(const bf16x8*)&sm.st.As[(wr * 64 + mi * 16 + r16) * 32 + kg * 8];
        #pragma unroll
        for (int ni = 0; ni < 4; ++ni)
            bv[ni] = *(const bf16x8*)&sm.st.Bs[(wc * 64 + ni * 16 + r16) * 32 + kg * 8];
        #pragma unroll
        for (int mi = 0; mi < 4; ++mi)
            #pragma unroll
            for (int ni = 0; ni < 4; ++ni)
                acc[mi][ni] = __builtin_amdgcn_mfma_f32_16x16x32_bf16(
                    af[mi], bv[ni], acc[mi][ni], 0, 0, 0);
        __syncthreads();   // protect LDS before next-stage overwrite
    }

    // ---- epilogue: per-wave LDS transpose -> coalesced wide stores ----
    // Source layout: acc[mi][ni][i] at row = mi*16 + (lane>>4)*4 + i,
    //                               col = ni*16 + (lane&15)   (quadrant-local)
    int c4 = lane & 15, rq = lane >> 4;
    int gn = n0 + wc * 64 + c4 * 4;
    float4 b4 = *(const float4*)&bias[gn];
    float* scr = sm.cscr[wave];    // 16 rows x 68 cols fp32 (own region per wave)
    #pragma unroll
    for (int mi = 0; mi < 4; ++mi) {
        #pragma unroll
        for (int ni = 0; ni < 4; ++ni)
            #pragma unroll
            for (int i = 0; i < 4; ++i)
                scr[(rq * 4 + i) * 68 + ni * 16 + c4] = acc[mi][ni][i];
        // same-wave DS pipeline is in-order: RAW/WAR safe without barrier
        #pragma unroll
        for (int j = 0; j < 4; ++j) {
            int row = j * 4 + rq;
            float4 v = *(const float4*)&scr[row * 68 + c4 * 4];
            int gm = m0 + wr * 64 + mi * 16 + row;
            v.x += b4.x; v.y += b4.y; v.z += b4.z; v.w += b4.w;
            if (MODE == 2) {
                float s = scale[(((gn >> 6) * 4) + (gm & 3)) * 64 + (gm >> 10)];
                ushort4 o;
                o.x = f2bf(v.x * s); o.y = f2bf(v.y * s);
                o.z = f2bf(v.z * s); o.w = f2bf(v.w * s);
                *(ushort4*)&Cb[(size_t)gm * N + gn] = o;
            } else {
                *(float4*)&Cf[(size_t)gm * N + gn] = v;
            }
        }
    }
}

extern "C" void kernel_launch(void* const* d_in, const int* in_sizes, int n_in,
                              void* d_out, int out_size, void* d_ws, size_t ws_size,
                              hipStream_t stream) {
    const float* x     = (const float*)d_in[0];
    const float* query = (const float*)d_in[1];
    const float* Wq    = (const float*)d_in[2];
    const float* bq    = (const float*)d_in[3];
    const float* Wk    = (const float*)d_in[4];
    const float* bk    = (const float*)d_in[5];
    const float* Wv    = (const float*)d_in[6];
    const float* bv    = (const float*)d_in[7];
    const float* Wo    = (const float*)d_in[8];
    const float* bo    = (const float*)d_in[9];
    float* out = (float*)d_out;

    // workspace layout (~208 MB)
    __hip_bfloat16* xb   = (__hip_bfloat16*)d_ws;        // 65536*768
    __hip_bfloat16* vtmp = xb + 50331648;                // 65536*768
    __hip_bfloat16* Wvb  = vtmp + 50331648;              // 768*768
    __hip_bfloat16* Wob  = Wvb + 589824;                 // 768*768
    float* xsum = (float*)(Wob + 589824);                // 256*768
    float* ksum = xsum + 196608;                         // 256*768
    float* qp   = ksum + 196608;                         // 1024*768
    float* psum = qp + 786432;                           // 12*4*64

    // 1) column-sum of x over c + x -> bf16 (float4 path)
    xsum_cvt_kernel<<<192, 256, 0, stream>>>((const float4*)x, (float4*)xsum, (ushort4*)xb);
    // 1b) weights -> bf16 (one dispatch)
    f2b_kernel<<<1152, 256, 0, stream>>>(Wv, Wo, (unsigned short*)Wvb, (unsigned short*)Wob);
    // 2+3) ksum and qp in one dispatch
    small_gemms<<<dim3(12, 20), 256, 0, stream>>>(xsum, Wk, bk, ksum, query, Wq, bq, qp);
    // 4) psum = sum_q softmax_r(qp . ksum)
    attn_kernel<<<48, 256, 0, stream>>>(qp, ksum, psum);
    // 5) vtmp = bf16((xb @ Wvb^T + bv) * psum)   MFMA  (65536 x 768 x 768)
    mfma_gemm<2><<<dim3(6, 512), 256, 0, stream>>>(
        (const ushort*)xb, (const ushort*)Wvb, bv, psum, nullptr, vtmp, 65536, 768, 768);
    // 6) out = vtmp @ Wob^T + bo                 MFMA  (65536 x 768 x 768)
    mfma_gemm<3><<<dim3(6, 512), 256, 0, stream>>>(
        (const ushort*)vtmp, (const ushort*)Wob, bo, nullptr, out, nullptr, 65536, 768, 768);
}